// Round 3
// baseline (2613.090 us; speedup 1.0000x reference)
//
#include <hip/hip_runtime.h>
#include <hip/hip_fp16.h>
#include <math.h>

#define BATCH 128
#define NDIM 512
#define NPAIR 256          // row-pairs per batch
#define POWER_ITERS 30
#define N_ITERS 500
#define KEEP 40            // row-pairs per thread in registers (of 64 owned)
#define LDSP 16            // row-pairs per thread in LDS
#define STRM 8             // row-pairs per thread streamed from L2

typedef _Float16 half2_t __attribute__((ext_vector_type(2)));

union H2x4 { float4 f4; half2_t h[4]; };

// ---------------- helpers ----------------
__device__ __forceinline__ float4 ld4(const float* p) { return *(const float4*)p; }
__device__ __forceinline__ float4 f4_add(float4 a, float4 b) {
  return make_float4(a.x + b.x, a.y + b.y, a.z + b.z, a.w + b.w);
}
__device__ __forceinline__ float wave_sum64(float x) {
#pragma unroll
  for (int off = 1; off < 64; off <<= 1) x += __shfl_xor(x, off, 64);
  return x;
}
__device__ __forceinline__ float wave_max64(float x) {
#pragma unroll
  for (int off = 1; off < 64; off <<= 1) x = fmaxf(x, __shfl_xor(x, off, 64));
  return x;
}
// 4 col-accumulators += one row-pair (16B of fp16) * y-pair, via v_dot2_f32_f16
__device__ __forceinline__ void fd4(float4 sv, half2_t yy,
                                    float& a0, float& a1, float& a2, float& a3) {
  H2x4 s; s.f4 = sv;
  a0 = __builtin_amdgcn_fdot2(s.h[0], yy, a0, false);
  a1 = __builtin_amdgcn_fdot2(s.h[1], yy, a1, false);
  a2 = __builtin_amdgcn_fdot2(s.h[2], yy, a2, false);
  a3 = __builtin_amdgcn_fdot2(s.h[3], yy, a3, false);
}

// ============ fp16 path ============
// ---- conversion: Sh[b][pair][col] = half2( sym(2p,col), sym(2p+1,col) ) ----
__global__ void sym_conv_kernel(const float* __restrict__ S, half2_t* __restrict__ Sh) {
  const int bb = blockIdx.x, ti = blockIdx.y, tj = blockIdx.z;
  if (tj < ti) return;
  __shared__ float ta[32][33];
  __shared__ float tb[32][33];
  const float* base = S + (size_t)bb * NDIM * NDIM;
  half2_t* dst = Sh + (size_t)bb * NPAIR * NDIM;
  const int tx = threadIdx.x, ty = threadIdx.y;  // 32 x 8
#pragma unroll
  for (int k = 0; k < 4; k++) {
    int r = ty + 8 * k;
    ta[r][tx] = base[(size_t)(ti * 32 + r) * NDIM + tj * 32 + tx];
    tb[r][tx] = base[(size_t)(tj * 32 + r) * NDIM + ti * 32 + tx];
  }
  __syncthreads();
#pragma unroll
  for (int k = 0; k < 2; k++) {
    int pi = ty + 8 * k;  // local pair 0..15
    float v0 = 0.5f * (ta[2 * pi][tx] + tb[tx][2 * pi]);
    float v1 = 0.5f * (ta[2 * pi + 1][tx] + tb[tx][2 * pi + 1]);
    half2_t o; o[0] = (_Float16)v0; o[1] = (_Float16)v1;
    dst[(size_t)(ti * 16 + pi) * NDIM + tj * 32 + tx] = o;
  }
  if (ti != tj) {
#pragma unroll
    for (int k = 0; k < 2; k++) {
      int pi = ty + 8 * k;
      float v0 = 0.5f * (tb[2 * pi][tx] + ta[tx][2 * pi]);
      float v1 = 0.5f * (tb[2 * pi + 1][tx] + ta[tx][2 * pi + 1]);
      half2_t o; o[0] = (_Float16)v0; o[1] = (_Float16)v1;
      dst[(size_t)(tj * 16 + pi) * NDIM + ti * 32 + tx] = o;
    }
  }
}

__device__ __forceinline__ void combine_z(const float* __restrict__ zsc, int lane, float* z8) {
#pragma unroll
  for (int q = 0; q < 2; q++) {
    float4 zz = ld4(zsc + 0 * NDIM + 8 * lane + 4 * q);
    zz = f4_add(zz, ld4(zsc + 1 * NDIM + 8 * lane + 4 * q));
    zz = f4_add(zz, ld4(zsc + 2 * NDIM + 8 * lane + 4 * q));
    zz = f4_add(zz, ld4(zsc + 3 * NDIM + 8 * lane + 4 * q));
    z8[4 * q + 0] = zz.x; z8[4 * q + 1] = zz.y;
    z8[4 * q + 2] = zz.z; z8[4 * q + 3] = zz.w;
  }
}

__device__ __forceinline__ void store_y_pairs(half2_t* ysh, int lane, const float* y8) {
  H2x4 yo;
#pragma unroll
  for (int q = 0; q < 4; q++) {
    half2_t v; v[0] = (_Float16)y8[2 * q]; v[1] = (_Float16)y8[2 * q + 1];
    yo.h[q] = v;
  }
  *(float4*)(ysh + 4 * lane) = yo.f4;
}

// Merged loop: iters [0,30) power, iter 30 = lambda/step, then FISTA.
// Matrix residency per thread (owns 64 pairs x 4 cols):
//   pairs  0..39 -> registers (float4 sreg[40], 160 VGPR)
//   pairs 40..55 -> LDS (128 KB; each thread reads back its own writes)
//   pairs 56..63 -> streamed from L2 (8-deep batch, 1 MB/XCD footprint)
// amdgpu_waves_per_eu(2,2): LDS already forces 1 block/CU = 2 waves/SIMD;
// pin the regalloc target there so the VGPR budget is 256, not the default 128.
__global__ __launch_bounds__(512) __attribute__((amdgpu_waves_per_eu(2, 2)))
void qp_solver_h(const float* __restrict__ mu,
                 const half2_t* __restrict__ Sh,
                 float* __restrict__ out) {
  __shared__ __align__(16) float4 lsm[4 * LDSP][128];  // 128 KB matrix slice
  __shared__ __align__(16) half2_t yh2[NPAIR];         // y as row-pairs (fp16)
  __shared__ __align__(16) float zsc[4 * NDIM];        // matvec partials per group
  __shared__ int stopf;
  const int tid = threadIdx.x;
  const int g = tid >> 7;        // 4 groups x 128 threads; group owns 64 row-pairs
  const int c = tid & 127;       // cols 4c..4c+3
  const int b = blockIdx.x;
  const half2_t* Sb = Sh + (size_t)b * NPAIR * NDIM;
  const float invn = 1.0f / (float)NDIM;
  const half2_t* rp = Sb + (size_t)(64 * g) * NDIM + 4 * c;     // this thread's slab base
  const half2_t* gp = rp + (size_t)(KEEP + LDSP) * NDIM;        // stream base (8 pairs)

  // register-resident slab: pairs [64g, 64g+KEEP)
  float4 sreg[KEEP];
#pragma unroll
  for (int p = 0; p < KEEP; p++) sreg[p] = *(const float4*)(rp + (size_t)p * NDIM);
  // LDS-resident slice: pairs [64g+KEEP, 64g+KEEP+LDSP)  (self-read, no sync needed)
#pragma unroll
  for (int k = 0; k < LDSP; k++)
    lsm[g * LDSP + k][c] = *(const float4*)(rp + (size_t)(KEEP + k) * NDIM);

  if (tid < NPAIR) { half2_t v; v[0] = (_Float16)invn; v[1] = (_Float16)invn; yh2[tid] = v; }
  if (tid == 0) stopf = 0;

  float y8[8], w8[8], mu8[8];
  float t = 1.0f, step = 0.f, maxinc = 0.f;
  if (tid < 64) {
    float4 m0 = ld4(mu + (size_t)b * NDIM + 8 * tid);
    float4 m1 = ld4(mu + (size_t)b * NDIM + 8 * tid + 4);
    mu8[0] = m0.x; mu8[1] = m0.y; mu8[2] = m0.z; mu8[3] = m0.w;
    mu8[4] = m1.x; mu8[5] = m1.y; mu8[6] = m1.z; mu8[7] = m1.w;
#pragma unroll
    for (int k = 0; k < 8; k++) { y8[k] = invn; w8[k] = invn; }
  }
  __syncthreads();

  const int TOT = POWER_ITERS + 1 + N_ITERS;
  for (int it = 0; it < TOT; it++) {
    // ---------- matvec: z[4c..4c+3] partial over this group's 64 pairs ----------
    float a0 = 0.f, a1 = 0.f, a2 = 0.f, a3 = 0.f;
    {
      const half2_t* ybase = yh2 + 64 * g;
      float4 stA[STRM];
      // issue all 8 stream loads up front; latency hides under the register burst
#pragma unroll
      for (int k = 0; k < STRM; k++) stA[k] = *(const float4*)(gp + (size_t)k * NDIM);
      // register slab: pairs 0..39 (160 fdot2)
#pragma unroll
      for (int ch = 0; ch < KEEP / 4; ch++) {
        H2x4 y4; y4.f4 = *(const float4*)(ybase + 4 * ch);
#pragma unroll
        for (int q = 0; q < 4; q++) fd4(sreg[4 * ch + q], y4.h[q], a0, a1, a2, a3);
      }
      // LDS slice: pairs 40..55 (64 fdot2)
#pragma unroll
      for (int k = 0; k < LDSP; k++)
        fd4(lsm[g * LDSP + k][c], ybase[KEEP + k], a0, a1, a2, a3);
      // streamed: pairs 56..63
#pragma unroll
      for (int k = 0; k < STRM; k++) fd4(stA[k], ybase[KEEP + LDSP + k], a0, a1, a2, a3);
    }
    *(float4*)(zsc + g * NDIM + 4 * c) = make_float4(a0, a1, a2, a3);
    __syncthreads();

    // ---------- serial phase (wave 0) ----------
    if (tid < 64) {
      float z8[8];
      combine_z(zsc, tid, z8);
      if (it < POWER_ITERS) {
        float ss = 0.f;
#pragma unroll
        for (int k = 0; k < 8; k++) ss += z8[k] * z8[k];
        ss = wave_sum64(ss);
        float inv = 1.0f / (sqrtf(ss) + 1e-12f);
#pragma unroll
        for (int k = 0; k < 8; k++) y8[k] = z8[k] * inv;
        store_y_pairs(yh2, tid, y8);
      } else if (it == POWER_ITERS) {
        float dd = 0.f;
#pragma unroll
        for (int k = 0; k < 8; k++) dd += z8[k] * y8[k];
        dd = wave_sum64(dd);
        step = 1.0f / (2.0f * dd + 1e-8f);
#pragma unroll
        for (int k = 0; k < 8; k++) { y8[k] = invn; w8[k] = invn; }
        t = 1.0f; maxinc = 0.f;
        store_y_pairs(yh2, tid, y8);
      } else {
        float v8[8];
        float s0 = 0.f;
#pragma unroll
        for (int k = 0; k < 8; k++) {
          v8[k] = y8[k] - step * (2.0f * z8[k] - mu8[k]);
          s0 += v8[k];
        }
        // Michelot round 1 fused: all elements active, cn = 512 (exact pow2)
        s0 = wave_sum64(s0);
        float th = (s0 - 1.0f) * (1.0f / 512.0f);
        for (int m = 0; m < 48; m++) {
          float s = 0.f, cn = 0.f;
#pragma unroll
          for (int k = 0; k < 8; k++)
            if (v8[k] > th) { s += v8[k]; cn += 1.f; }
#pragma unroll
          for (int off = 1; off < 64; off <<= 1) {
            s  += __shfl_xor(s, off, 64);
            cn += __shfl_xor(cn, off, 64);
          }
          float thn = (s - 1.0f) / cn;
          if (!(thn > th)) break;
          th = thn;
        }
        float tn = 0.5f * (1.0f + sqrtf(1.0f + 4.0f * t * t));
        float coef = (t - 1.0f) / tn;
#pragma unroll
        for (int k = 0; k < 8; k++) {
          float wn = fmaxf(v8[k] - th, 0.0f);
          maxinc = fmaxf(maxinc, fabsf(wn - w8[k]));
          y8[k] = wn + coef * (wn - w8[k]);
          w8[k] = wn;
        }
        t = tn;
        store_y_pairs(yh2, tid, y8);
        // convergence reduce amortized over 4 iterations
        if ((it & 3) == 3) {
          float mi = wave_max64(maxinc);
          if (tid == 0) stopf = (mi < 1e-7f) ? (stopf + 1) : 0;
          maxinc = 0.f;
        }
      }
    }
    __syncthreads();
    if (stopf >= 2) break;
  }

  if (tid < 64) {
    *(float4*)(out + (size_t)b * NDIM + 8 * tid)     = make_float4(w8[0], w8[1], w8[2], w8[3]);
    *(float4*)(out + (size_t)b * NDIM + 8 * tid + 4) = make_float4(w8[4], w8[5], w8[6], w8[7]);
  }
}

// ============ fp32 fallback path (used only if ws too small) ============
__global__ void symmetrize_kernel(float* __restrict__ S) {
  const int ti = blockIdx.y, tj = blockIdx.z;
  if (tj < ti) return;
  __shared__ float ta[32][33];
  __shared__ float tb[32][33];
  float* base = S + (size_t)blockIdx.x * NDIM * NDIM;
  const int tx = threadIdx.x, ty = threadIdx.y;
#pragma unroll
  for (int k = 0; k < 4; k++) {
    int r = ty + 8 * k;
    ta[r][tx] = base[(size_t)(ti * 32 + r) * NDIM + tj * 32 + tx];
    tb[r][tx] = base[(size_t)(tj * 32 + r) * NDIM + ti * 32 + tx];
  }
  __syncthreads();
#pragma unroll
  for (int k = 0; k < 4; k++) {
    int r = ty + 8 * k;
    base[(size_t)(ti * 32 + r) * NDIM + tj * 32 + tx] = 0.5f * (ta[r][tx] + tb[tx][r]);
  }
#pragma unroll
  for (int k = 0; k < 4; k++) {
    int r = ty + 8 * k;
    base[(size_t)(tj * 32 + r) * NDIM + ti * 32 + tx] = 0.5f * (tb[r][tx] + ta[tx][r]);
  }
}

__device__ __forceinline__ float4 f4_fma(float4 a, float s, float4 acc) {
  acc.x = fmaf(a.x, s, acc.x); acc.y = fmaf(a.y, s, acc.y);
  acc.z = fmaf(a.z, s, acc.z); acc.w = fmaf(a.w, s, acc.w);
  return acc;
}
__device__ __forceinline__ void matvec_partial(const float* __restrict__ Sb,
                                               const float* __restrict__ yv,
                                               float* __restrict__ zsc, int g, int c) {
  const float* rp = Sb + (size_t)(g * 128) * NDIM + 4 * c;
  const float* yp = yv + g * 128;
  float4 a0 = make_float4(0, 0, 0, 0), a1 = a0, a2 = a0, a3 = a0;
#pragma unroll 4
  for (int m = 0; m < 32; m++) {
    float4 yq = ld4(yp + 4 * m);
    float4 s0 = ld4(rp + (size_t)(4 * m + 0) * NDIM);
    float4 s1 = ld4(rp + (size_t)(4 * m + 1) * NDIM);
    float4 s2 = ld4(rp + (size_t)(4 * m + 2) * NDIM);
    float4 s3 = ld4(rp + (size_t)(4 * m + 3) * NDIM);
    a0 = f4_fma(s0, yq.x, a0); a1 = f4_fma(s1, yq.y, a1);
    a2 = f4_fma(s2, yq.z, a2); a3 = f4_fma(s3, yq.w, a3);
  }
  float4 z = f4_add(f4_add(a0, a1), f4_add(a2, a3));
  *(float4*)(zsc + g * NDIM + 4 * c) = z;
}

__launch_bounds__(512, 1)
__global__ void qp_solver(const float* __restrict__ mu,
                          const float* __restrict__ S,
                          float* __restrict__ out) {
  __shared__ float yv[NDIM];
  __shared__ float zsc[4 * NDIM];
  __shared__ float bc[1];
  const int tid = threadIdx.x, g = tid >> 7, c = tid & 127, b = blockIdx.x;
  const float* Sb = S + (size_t)b * NDIM * NDIM;
  const float invn = 1.0f / (float)NDIM;
  yv[tid] = invn;
  __syncthreads();
  for (int it = 0; it < POWER_ITERS; it++) {
    matvec_partial(Sb, yv, zsc, g, c);
    __syncthreads();
    if (tid < 64) {
      float z8[8]; combine_z(zsc, tid, z8);
      float ss = 0.f;
#pragma unroll
      for (int k = 0; k < 8; k++) ss += z8[k] * z8[k];
      ss = wave_sum64(ss);
      float inv = 1.0f / (sqrtf(ss) + 1e-12f);
      *(float4*)(yv + 8 * tid)     = make_float4(z8[0]*inv, z8[1]*inv, z8[2]*inv, z8[3]*inv);
      *(float4*)(yv + 8 * tid + 4) = make_float4(z8[4]*inv, z8[5]*inv, z8[6]*inv, z8[7]*inv);
    }
    __syncthreads();
  }
  matvec_partial(Sb, yv, zsc, g, c);
  __syncthreads();
  if (tid < 64) {
    float z8[8]; combine_z(zsc, tid, z8);
    float dd = 0.f;
#pragma unroll
    for (int k = 0; k < 8; k++) dd += z8[k] * yv[8 * tid + k];
    dd = wave_sum64(dd);
    if (tid == 0) bc[0] = 1.0f / (2.0f * dd + 1e-8f);
  }
  __syncthreads();
  const float step = bc[0];
  yv[tid] = invn;
  float w8[8], y8[8], mu8[8];
  if (tid < 64) {
#pragma unroll
    for (int k = 0; k < 8; k++) { w8[k] = invn; y8[k] = invn; }
    float4 m0 = ld4(mu + (size_t)b * NDIM + 8 * tid);
    float4 m1 = ld4(mu + (size_t)b * NDIM + 8 * tid + 4);
    mu8[0] = m0.x; mu8[1] = m0.y; mu8[2] = m0.z; mu8[3] = m0.w;
    mu8[4] = m1.x; mu8[5] = m1.y; mu8[6] = m1.z; mu8[7] = m1.w;
  }
  __syncthreads();
  float t = 1.0f;
  for (int it = 0; it < N_ITERS; it++) {
    matvec_partial(Sb, yv, zsc, g, c);
    __syncthreads();
    if (tid < 64) {
      float z8[8], v8[8]; combine_z(zsc, tid, z8);
#pragma unroll
      for (int k = 0; k < 8; k++) v8[k] = y8[k] - step * (2.0f * z8[k] - mu8[k]);
      float th = -1e30f;
      for (int m = 0; m < 64; m++) {
        float s = 0.f, cn = 0.f;
#pragma unroll
        for (int k = 0; k < 8; k++) if (v8[k] > th) { s += v8[k]; cn += 1.f; }
#pragma unroll
        for (int off = 1; off < 64; off <<= 1) { s += __shfl_xor(s, off, 64); cn += __shfl_xor(cn, off, 64); }
        float thn = (s - 1.0f) / cn;
        if (!(thn > th)) break;
        th = thn;
      }
      float tn = 0.5f * (1.0f + sqrtf(1.0f + 4.0f * t * t));
      float coef = (t - 1.0f) / tn;
#pragma unroll
      for (int k = 0; k < 8; k++) {
        float wn = fmaxf(v8[k] - th, 0.0f);
        y8[k] = wn + coef * (wn - w8[k]);
        w8[k] = wn;
      }
      *(float4*)(yv + 8 * tid)     = make_float4(y8[0], y8[1], y8[2], y8[3]);
      *(float4*)(yv + 8 * tid + 4) = make_float4(y8[4], y8[5], y8[6], y8[7]);
      t = tn;
    }
    __syncthreads();
  }
  if (tid < 64) {
    *(float4*)(out + (size_t)b * NDIM + 8 * tid)     = make_float4(w8[0], w8[1], w8[2], w8[3]);
    *(float4*)(out + (size_t)b * NDIM + 8 * tid + 4) = make_float4(w8[4], w8[5], w8[6], w8[7]);
  }
}

// ---------------- launch ----------------
extern "C" void kernel_launch(void* const* d_in, const int* in_sizes, int n_in,
                              void* d_out, int out_size, void* d_ws, size_t ws_size,
                              hipStream_t stream) {
  const float* mu = (const float*)d_in[0];
  float* Sg = (float*)d_in[1];
  if (n_in >= 2 && in_sizes[0] > in_sizes[1]) { mu = (const float*)d_in[1]; Sg = (float*)d_in[0]; }
  float* out = (float*)d_out;

  const size_t need = (size_t)BATCH * NPAIR * NDIM * sizeof(half2_t);  // 64 MB
  if (ws_size >= need) {
    half2_t* Sh = (half2_t*)d_ws;
    sym_conv_kernel<<<dim3(BATCH, 16, 16), dim3(32, 8), 0, stream>>>(Sg, Sh);
    qp_solver_h<<<dim3(BATCH), dim3(512), 0, stream>>>(mu, Sh, out);
  } else {
    symmetrize_kernel<<<dim3(BATCH, 16, 16), dim3(32, 8), 0, stream>>>(Sg);
    qp_solver<<<dim3(BATCH), dim3(512), 0, stream>>>(mu, Sg, out);
  }
}

// Round 4
// 1715.369 us; speedup vs baseline: 1.5233x; 1.5233x over previous
//
#include <hip/hip_runtime.h>
#include <hip/hip_fp16.h>
#include <math.h>

#define BATCH 128
#define NDIM 512
#define NPAIR 256          // row-pairs per batch
#define POWER_ITERS 30
#define N_ITERS 500
#define KEEP 40            // row-pairs per thread in registers (of 64 owned)
#define LDSP 16            // row-pairs per thread in LDS
#define STRM 8             // row-pairs per thread streamed from L2

typedef _Float16 half2_t __attribute__((ext_vector_type(2)));

union H2x4 { float4 f4; half2_t h[4]; };

// ---------------- helpers ----------------
__device__ __forceinline__ float4 ld4(const float* p) { return *(const float4*)p; }
__device__ __forceinline__ float4 f4_add(float4 a, float4 b) {
  return make_float4(a.x + b.x, a.y + b.y, a.z + b.z, a.w + b.w);
}
__device__ __forceinline__ float wave_sum64(float x) {
#pragma unroll
  for (int off = 1; off < 64; off <<= 1) x += __shfl_xor(x, off, 64);
  return x;
}
__device__ __forceinline__ float wave_max64(float x) {
#pragma unroll
  for (int off = 1; off < 64; off <<= 1) x = fmaxf(x, __shfl_xor(x, off, 64));
  return x;
}
// 4 col-accumulators += one row-pair (16B of fp16) * y-pair, via v_dot2_f32_f16
__device__ __forceinline__ void fd4(float4 sv, half2_t yy,
                                    float& a0, float& a1, float& a2, float& a3) {
  H2x4 s; s.f4 = sv;
  a0 = __builtin_amdgcn_fdot2(s.h[0], yy, a0, false);
  a1 = __builtin_amdgcn_fdot2(s.h[1], yy, a1, false);
  a2 = __builtin_amdgcn_fdot2(s.h[2], yy, a2, false);
  a3 = __builtin_amdgcn_fdot2(s.h[3], yy, a3, false);
}

// ============ fp16 path ============
// ---- conversion: Sh[b][pair][col] = half2( sym(2p,col), sym(2p+1,col) ) ----
__global__ void sym_conv_kernel(const float* __restrict__ S, half2_t* __restrict__ Sh) {
  const int bb = blockIdx.x, ti = blockIdx.y, tj = blockIdx.z;
  if (tj < ti) return;
  __shared__ float ta[32][33];
  __shared__ float tb[32][33];
  const float* base = S + (size_t)bb * NDIM * NDIM;
  half2_t* dst = Sh + (size_t)bb * NPAIR * NDIM;
  const int tx = threadIdx.x, ty = threadIdx.y;  // 32 x 8
#pragma unroll
  for (int k = 0; k < 4; k++) {
    int r = ty + 8 * k;
    ta[r][tx] = base[(size_t)(ti * 32 + r) * NDIM + tj * 32 + tx];
    tb[r][tx] = base[(size_t)(tj * 32 + r) * NDIM + ti * 32 + tx];
  }
  __syncthreads();
#pragma unroll
  for (int k = 0; k < 2; k++) {
    int pi = ty + 8 * k;  // local pair 0..15
    float v0 = 0.5f * (ta[2 * pi][tx] + tb[tx][2 * pi]);
    float v1 = 0.5f * (ta[2 * pi + 1][tx] + tb[tx][2 * pi + 1]);
    half2_t o; o[0] = (_Float16)v0; o[1] = (_Float16)v1;
    dst[(size_t)(ti * 16 + pi) * NDIM + tj * 32 + tx] = o;
  }
  if (ti != tj) {
#pragma unroll
    for (int k = 0; k < 2; k++) {
      int pi = ty + 8 * k;
      float v0 = 0.5f * (tb[2 * pi][tx] + ta[tx][2 * pi]);
      float v1 = 0.5f * (tb[2 * pi + 1][tx] + ta[tx][2 * pi + 1]);
      half2_t o; o[0] = (_Float16)v0; o[1] = (_Float16)v1;
      dst[(size_t)(tj * 16 + pi) * NDIM + ti * 32 + tx] = o;
    }
  }
}

__device__ __forceinline__ void combine_z(const float* __restrict__ zsc, int lane, float* z8) {
#pragma unroll
  for (int q = 0; q < 2; q++) {
    float4 zz = ld4(zsc + 0 * NDIM + 8 * lane + 4 * q);
    zz = f4_add(zz, ld4(zsc + 1 * NDIM + 8 * lane + 4 * q));
    zz = f4_add(zz, ld4(zsc + 2 * NDIM + 8 * lane + 4 * q));
    zz = f4_add(zz, ld4(zsc + 3 * NDIM + 8 * lane + 4 * q));
    z8[4 * q + 0] = zz.x; z8[4 * q + 1] = zz.y;
    z8[4 * q + 2] = zz.z; z8[4 * q + 3] = zz.w;
  }
}

__device__ __forceinline__ void store_y_pairs(half2_t* ysh, int lane, const float* y8) {
  H2x4 yo;
#pragma unroll
  for (int q = 0; q < 4; q++) {
    half2_t v; v[0] = (_Float16)y8[2 * q]; v[1] = (_Float16)y8[2 * q + 1];
    yo.h[q] = v;
  }
  *(float4*)(ysh + 4 * lane) = yo.f4;
}

// Merged loop: iters [0,30) power, iter 30 = lambda/step, then FISTA.
// Matrix residency per thread (owns 64 pairs x 4 cols):
//   pairs  0..39 -> registers (float4 sreg[40], 160 VGPR)
//   pairs 40..55 -> LDS (128 KB; each thread reads back its own writes)
//   pairs 56..63 -> streamed from L2 (8-deep batch)
// amdgpu_flat_work_group_size(512,512) + amdgpu_waves_per_eu(2):
// exact workgroup size, min 2 waves/EU -> regalloc budget 512/2 = 256 VGPRs.
// (__launch_bounds__ deliberately absent: testing whether its expansion was
//  what pinned the budget to 128.)
__global__ __attribute__((amdgpu_flat_work_group_size(512, 512)))
__attribute__((amdgpu_waves_per_eu(2)))
void qp_solver_h(const float* __restrict__ mu,
                 const half2_t* __restrict__ Sh,
                 float* __restrict__ out) {
  __shared__ __align__(16) float4 lsm[4 * LDSP][128];  // 128 KB matrix slice
  __shared__ __align__(16) half2_t yh2[NPAIR];         // y as row-pairs (fp16)
  __shared__ __align__(16) float zsc[4 * NDIM];        // matvec partials per group
  __shared__ int stopf;
  const int tid = threadIdx.x;
  const int g = tid >> 7;        // 4 groups x 128 threads; group owns 64 row-pairs
  const int c = tid & 127;       // cols 4c..4c+3
  const int b = blockIdx.x;
  const half2_t* Sb = Sh + (size_t)b * NPAIR * NDIM;
  const float invn = 1.0f / (float)NDIM;
  const half2_t* rp = Sb + (size_t)(64 * g) * NDIM + 4 * c;     // this thread's slab base
  const half2_t* gp = rp + (size_t)(KEEP + LDSP) * NDIM;        // stream base (8 pairs)

  // register-resident slab: pairs [64g, 64g+KEEP)
  float4 sreg[KEEP];
#pragma unroll
  for (int p = 0; p < KEEP; p++) sreg[p] = *(const float4*)(rp + (size_t)p * NDIM);
  // LDS-resident slice: pairs [64g+KEEP, 64g+KEEP+LDSP)  (self-read, no sync needed)
#pragma unroll
  for (int k = 0; k < LDSP; k++)
    lsm[g * LDSP + k][c] = *(const float4*)(rp + (size_t)(KEEP + k) * NDIM);

  if (tid < NPAIR) { half2_t v; v[0] = (_Float16)invn; v[1] = (_Float16)invn; yh2[tid] = v; }
  if (tid == 0) stopf = 0;

  float y8[8], w8[8], mu8[8];
  float t = 1.0f, step = 0.f, maxinc = 0.f;
  float th = -3e38f;             // warm-start simplex threshold (wave0-persistent)
  if (tid < 64) {
    float4 m0 = ld4(mu + (size_t)b * NDIM + 8 * tid);
    float4 m1 = ld4(mu + (size_t)b * NDIM + 8 * tid + 4);
    mu8[0] = m0.x; mu8[1] = m0.y; mu8[2] = m0.z; mu8[3] = m0.w;
    mu8[4] = m1.x; mu8[5] = m1.y; mu8[6] = m1.z; mu8[7] = m1.w;
#pragma unroll
    for (int k = 0; k < 8; k++) { y8[k] = invn; w8[k] = invn; }
  }
  __syncthreads();

  const int TOT = POWER_ITERS + 1 + N_ITERS;
  for (int it = 0; it < TOT; it++) {
    // ---------- matvec: z[4c..4c+3] partial over this group's 64 pairs ----------
    float a0 = 0.f, a1 = 0.f, a2 = 0.f, a3 = 0.f;
    {
      const half2_t* ybase = yh2 + 64 * g;
      float4 stA[STRM];
      // issue all 8 stream loads up front; latency hides under the register burst
#pragma unroll
      for (int k = 0; k < STRM; k++) stA[k] = *(const float4*)(gp + (size_t)k * NDIM);
      // register slab: pairs 0..39 (160 fdot2)
#pragma unroll
      for (int ch = 0; ch < KEEP / 4; ch++) {
        H2x4 y4; y4.f4 = *(const float4*)(ybase + 4 * ch);
#pragma unroll
        for (int q = 0; q < 4; q++) fd4(sreg[4 * ch + q], y4.h[q], a0, a1, a2, a3);
      }
      // LDS slice: pairs 40..55 (64 fdot2)
#pragma unroll
      for (int k = 0; k < LDSP; k++)
        fd4(lsm[g * LDSP + k][c], ybase[KEEP + k], a0, a1, a2, a3);
      // streamed: pairs 56..63
#pragma unroll
      for (int k = 0; k < STRM; k++) fd4(stA[k], ybase[KEEP + LDSP + k], a0, a1, a2, a3);
    }
    *(float4*)(zsc + g * NDIM + 4 * c) = make_float4(a0, a1, a2, a3);
    __syncthreads();

    // ---------- serial phase (wave 0) ----------
    if (tid < 64) {
      float z8[8];
      combine_z(zsc, tid, z8);
      if (it < POWER_ITERS) {
        float ss = 0.f;
#pragma unroll
        for (int k = 0; k < 8; k++) ss += z8[k] * z8[k];
        ss = wave_sum64(ss);
        float inv = 1.0f / (sqrtf(ss) + 1e-12f);
#pragma unroll
        for (int k = 0; k < 8; k++) y8[k] = z8[k] * inv;
        store_y_pairs(yh2, tid, y8);
      } else if (it == POWER_ITERS) {
        float dd = 0.f;
#pragma unroll
        for (int k = 0; k < 8; k++) dd += z8[k] * y8[k];
        dd = wave_sum64(dd);
        step = 1.0f / (2.0f * dd + 1e-8f);
#pragma unroll
        for (int k = 0; k < 8; k++) { y8[k] = invn; w8[k] = invn; }
        t = 1.0f; maxinc = 0.f;
        store_y_pairs(yh2, tid, y8);
      } else {
        float v8[8];
#pragma unroll
        for (int k = 0; k < 8; k++)
          v8[k] = y8[k] - step * (2.0f * z8[k] - mu8[k]);

        // ---- warm-started two-sided Michelot simplex projection ----
        // Forced round from th_prev. Property: T(th) <= th* for th >= th*,
        // and T(th) <= th* for th <= th* (Michelot), so after this round we
        // are at/below th* and the from-below loop converges monotonically.
        {
          float s = 0.f, cn = 0.f, stot = 0.f;
#pragma unroll
          for (int k = 0; k < 8; k++) {
            stot += v8[k];
            if (v8[k] > th) { s += v8[k]; cn += 1.f; }
          }
#pragma unroll
          for (int off = 1; off < 64; off <<= 1) {
            s    += __shfl_xor(s, off, 64);
            cn   += __shfl_xor(cn, off, 64);
            stot += __shfl_xor(stot, off, 64);
          }
          th = (cn > 0.f) ? (s - 1.0f) / cn
                          : (stot - 1.0f) * (1.0f / 512.0f);  // guard: empty set
        }
        // from-below fixed-point iterations (typically 1-2 near convergence)
        for (int m = 0; m < 16; m++) {
          float s = 0.f, cn = 0.f;
#pragma unroll
          for (int k = 0; k < 8; k++)
            if (v8[k] > th) { s += v8[k]; cn += 1.f; }
#pragma unroll
          for (int off = 1; off < 64; off <<= 1) {
            s  += __shfl_xor(s, off, 64);
            cn += __shfl_xor(cn, off, 64);
          }
          float thn = (s - 1.0f) / cn;
          if (!(thn > th)) break;
          th = thn;
        }

        float tn = 0.5f * (1.0f + sqrtf(1.0f + 4.0f * t * t));
        float coef = (t - 1.0f) / tn;
#pragma unroll
        for (int k = 0; k < 8; k++) {
          float wn = fmaxf(v8[k] - th, 0.0f);
          maxinc = fmaxf(maxinc, fabsf(wn - w8[k]));
          y8[k] = wn + coef * (wn - w8[k]);
          w8[k] = wn;
        }
        t = tn;
        store_y_pairs(yh2, tid, y8);
        // convergence reduce amortized over 4 iterations
        if ((it & 3) == 3) {
          float mi = wave_max64(maxinc);
          if (tid == 0) stopf = (mi < 1e-7f) ? (stopf + 1) : 0;
          maxinc = 0.f;
        }
      }
    }
    __syncthreads();
    if (stopf >= 2) break;
  }

  if (tid < 64) {
    *(float4*)(out + (size_t)b * NDIM + 8 * tid)     = make_float4(w8[0], w8[1], w8[2], w8[3]);
    *(float4*)(out + (size_t)b * NDIM + 8 * tid + 4) = make_float4(w8[4], w8[5], w8[6], w8[7]);
  }
}

// ============ fp32 fallback path (used only if ws too small) ============
__global__ void symmetrize_kernel(float* __restrict__ S) {
  const int ti = blockIdx.y, tj = blockIdx.z;
  if (tj < ti) return;
  __shared__ float ta[32][33];
  __shared__ float tb[32][33];
  float* base = S + (size_t)blockIdx.x * NDIM * NDIM;
  const int tx = threadIdx.x, ty = threadIdx.y;
#pragma unroll
  for (int k = 0; k < 4; k++) {
    int r = ty + 8 * k;
    ta[r][tx] = base[(size_t)(ti * 32 + r) * NDIM + tj * 32 + tx];
    tb[r][tx] = base[(size_t)(tj * 32 + r) * NDIM + ti * 32 + tx];
  }
  __syncthreads();
#pragma unroll
  for (int k = 0; k < 4; k++) {
    int r = ty + 8 * k;
    base[(size_t)(ti * 32 + r) * NDIM + tj * 32 + tx] = 0.5f * (ta[r][tx] + tb[tx][r]);
  }
#pragma unroll
  for (int k = 0; k < 4; k++) {
    int r = ty + 8 * k;
    base[(size_t)(tj * 32 + r) * NDIM + ti * 32 + tx] = 0.5f * (tb[r][tx] + ta[tx][r]);
  }
}

__device__ __forceinline__ float4 f4_fma(float4 a, float s, float4 acc) {
  acc.x = fmaf(a.x, s, acc.x); acc.y = fmaf(a.y, s, acc.y);
  acc.z = fmaf(a.z, s, acc.z); acc.w = fmaf(a.w, s, acc.w);
  return acc;
}
__device__ __forceinline__ void matvec_partial(const float* __restrict__ Sb,
                                               const float* __restrict__ yv,
                                               float* __restrict__ zsc, int g, int c) {
  const float* rp = Sb + (size_t)(g * 128) * NDIM + 4 * c;
  const float* yp = yv + g * 128;
  float4 a0 = make_float4(0, 0, 0, 0), a1 = a0, a2 = a0, a3 = a0;
#pragma unroll 4
  for (int m = 0; m < 32; m++) {
    float4 yq = ld4(yp + 4 * m);
    float4 s0 = ld4(rp + (size_t)(4 * m + 0) * NDIM);
    float4 s1 = ld4(rp + (size_t)(4 * m + 1) * NDIM);
    float4 s2 = ld4(rp + (size_t)(4 * m + 2) * NDIM);
    float4 s3 = ld4(rp + (size_t)(4 * m + 3) * NDIM);
    a0 = f4_fma(s0, yq.x, a0); a1 = f4_fma(s1, yq.y, a1);
    a2 = f4_fma(s2, yq.z, a2); a3 = f4_fma(s3, yq.w, a3);
  }
  float4 z = f4_add(f4_add(a0, a1), f4_add(a2, a3));
  *(float4*)(zsc + g * NDIM + 4 * c) = z;
}

__launch_bounds__(512, 1)
__global__ void qp_solver(const float* __restrict__ mu,
                          const float* __restrict__ S,
                          float* __restrict__ out) {
  __shared__ float yv[NDIM];
  __shared__ float zsc[4 * NDIM];
  __shared__ float bc[1];
  const int tid = threadIdx.x, g = tid >> 7, c = tid & 127, b = blockIdx.x;
  const float* Sb = S + (size_t)b * NDIM * NDIM;
  const float invn = 1.0f / (float)NDIM;
  yv[tid] = invn;
  __syncthreads();
  for (int it = 0; it < POWER_ITERS; it++) {
    matvec_partial(Sb, yv, zsc, g, c);
    __syncthreads();
    if (tid < 64) {
      float z8[8]; combine_z(zsc, tid, z8);
      float ss = 0.f;
#pragma unroll
      for (int k = 0; k < 8; k++) ss += z8[k] * z8[k];
      ss = wave_sum64(ss);
      float inv = 1.0f / (sqrtf(ss) + 1e-12f);
      *(float4*)(yv + 8 * tid)     = make_float4(z8[0]*inv, z8[1]*inv, z8[2]*inv, z8[3]*inv);
      *(float4*)(yv + 8 * tid + 4) = make_float4(z8[4]*inv, z8[5]*inv, z8[6]*inv, z8[7]*inv);
    }
    __syncthreads();
  }
  matvec_partial(Sb, yv, zsc, g, c);
  __syncthreads();
  if (tid < 64) {
    float z8[8]; combine_z(zsc, tid, z8);
    float dd = 0.f;
#pragma unroll
    for (int k = 0; k < 8; k++) dd += z8[k] * yv[8 * tid + k];
    dd = wave_sum64(dd);
    if (tid == 0) bc[0] = 1.0f / (2.0f * dd + 1e-8f);
  }
  __syncthreads();
  const float step = bc[0];
  yv[tid] = invn;
  float w8[8], y8[8], mu8[8];
  if (tid < 64) {
#pragma unroll
    for (int k = 0; k < 8; k++) { w8[k] = invn; y8[k] = invn; }
    float4 m0 = ld4(mu + (size_t)b * NDIM + 8 * tid);
    float4 m1 = ld4(mu + (size_t)b * NDIM + 8 * tid + 4);
    mu8[0] = m0.x; mu8[1] = m0.y; mu8[2] = m0.z; mu8[3] = m0.w;
    mu8[4] = m1.x; mu8[5] = m1.y; mu8[6] = m1.z; mu8[7] = m1.w;
  }
  __syncthreads();
  float t = 1.0f;
  for (int it = 0; it < N_ITERS; it++) {
    matvec_partial(Sb, yv, zsc, g, c);
    __syncthreads();
    if (tid < 64) {
      float z8[8], v8[8]; combine_z(zsc, tid, z8);
#pragma unroll
      for (int k = 0; k < 8; k++) v8[k] = y8[k] - step * (2.0f * z8[k] - mu8[k]);
      float th = -1e30f;
      for (int m = 0; m < 64; m++) {
        float s = 0.f, cn = 0.f;
#pragma unroll
        for (int k = 0; k < 8; k++) if (v8[k] > th) { s += v8[k]; cn += 1.f; }
#pragma unroll
        for (int off = 1; off < 64; off <<= 1) { s += __shfl_xor(s, off, 64); cn += __shfl_xor(cn, off, 64); }
        float thn = (s - 1.0f) / cn;
        if (!(thn > th)) break;
        th = thn;
      }
      float tn = 0.5f * (1.0f + sqrtf(1.0f + 4.0f * t * t));
      float coef = (t - 1.0f) / tn;
#pragma unroll
      for (int k = 0; k < 8; k++) {
        float wn = fmaxf(v8[k] - th, 0.0f);
        y8[k] = wn + coef * (wn - w8[k]);
        w8[k] = wn;
      }
      *(float4*)(yv + 8 * tid)     = make_float4(y8[0], y8[1], y8[2], y8[3]);
      *(float4*)(yv + 8 * tid + 4) = make_float4(y8[4], y8[5], y8[6], y8[7]);
      t = tn;
    }
    __syncthreads();
  }
  if (tid < 64) {
    *(float4*)(out + (size_t)b * NDIM + 8 * tid)     = make_float4(w8[0], w8[1], w8[2], w8[3]);
    *(float4*)(out + (size_t)b * NDIM + 8 * tid + 4) = make_float4(w8[4], w8[5], w8[6], w8[7]);
  }
}

// ---------------- launch ----------------
extern "C" void kernel_launch(void* const* d_in, const int* in_sizes, int n_in,
                              void* d_out, int out_size, void* d_ws, size_t ws_size,
                              hipStream_t stream) {
  const float* mu = (const float*)d_in[0];
  float* Sg = (float*)d_in[1];
  if (n_in >= 2 && in_sizes[0] > in_sizes[1]) { mu = (const float*)d_in[1]; Sg = (float*)d_in[0]; }
  float* out = (float*)d_out;

  const size_t need = (size_t)BATCH * NPAIR * NDIM * sizeof(half2_t);  // 64 MB
  if (ws_size >= need) {
    half2_t* Sh = (half2_t*)d_ws;
    sym_conv_kernel<<<dim3(BATCH, 16, 16), dim3(32, 8), 0, stream>>>(Sg, Sh);
    qp_solver_h<<<dim3(BATCH), dim3(512), 0, stream>>>(mu, Sh, out);
  } else {
    symmetrize_kernel<<<dim3(BATCH, 16, 16), dim3(32, 8), 0, stream>>>(Sg);
    qp_solver<<<dim3(BATCH), dim3(512), 0, stream>>>(mu, Sg, out);
  }
}